// Round 4
// baseline (73.448 us; speedup 1.0000x reference)
//
#include <hip/hip_runtime.h>

#define NEG_INF  (-10000.0f)
#define L_SEQ    100
#define N_COLS   6464      // BS*(L+1)
#define D_       64
#define N_ROWS   6400      // BS*L
#define NSPLIT   8

// ws byte offsets
#define OFF_SCBF 0          // ushort[6464*64] = 827392 B
#define OFF_MD   827392     // float[64*6464] = 1654784 B
#define OFF_XT   2482176    // float[6400] = 25600 B
#define OFF_PS   2507776    // float[6400*8] = 204800 B
#define OFF_ACC  2712576    // float[2] sum,cnt
#define OFF_DONE 2712584    // u32[1]
// total 2712588 B

typedef __attribute__((ext_vector_type(8))) short short8;
typedef __attribute__((ext_vector_type(4))) float f32x4;
union F8 { short8 v; unsigned short u[8]; };

__device__ __forceinline__ unsigned short f2bf(float f) {
  unsigned u = __float_as_uint(f);
  unsigned r = (u + 0x7FFFu + ((u >> 16) & 1u)) >> 16;
  return (unsigned short)r;
}

// blocks 0..201  : score f32->bf16 (8 elems/thread)
// blocks 202..265: md[i][k] = (valid[k] && !dup[i][k]) ? 1/pop[sid[k]] : 0  (f32)
// blocks 266..290: exact f32 target logit xt[r] (NEG_INF if target col invalid)
// block  291     : zero accumulators
__global__ __launch_bounds__(256) void prep_kernel(
    const float* __restrict__ prec, const float* __restrict__ score,
    const float* __restrict__ pop, const int* __restrict__ sid,
    const int* __restrict__ lm,
    unsigned short* __restrict__ sc_bf, float* __restrict__ md,
    float* __restrict__ xt, float* __restrict__ acc, unsigned* __restrict__ done) {
  const int b = blockIdx.x, tid = threadIdx.x;
  __shared__ unsigned bset[3126];  // 100032 bits >= ITEM_NUM+1

  if (b < 202) {
    int g = b * 256 + tid;  // 51712 chunks of 8 floats
    const float4* sp = (const float4*)score + (size_t)g * 2;
    float4 a = sp[0], c = sp[1];
    F8 o;
    o.u[0] = f2bf(a.x); o.u[1] = f2bf(a.y); o.u[2] = f2bf(a.z); o.u[3] = f2bf(a.w);
    o.u[4] = f2bf(c.x); o.u[5] = f2bf(c.y); o.u[6] = f2bf(c.z); o.u[7] = f2bf(c.w);
    *((short8*)(sc_bf + (size_t)g * 8)) = o.v;
  } else if (b < 266) {
    const int i = b - 202;
    for (int w = tid; w < 3126; w += 256) bset[w] = 0u;
    __syncthreads();
    if (tid < 101) {
      int id = sid[i * 101 + tid];
      atomicOr(&bset[id >> 5], 1u << (id & 31));
    }
    __syncthreads();
    for (int k = tid; k < N_COLS; k += 256) {
      int id = sid[k];
      unsigned hit = (bset[id >> 5] >> (id & 31)) & 1u;
      int i2 = k / 101, p = k - i2 * 101;
      int v = (p == 100) ? 1 : lm[i2 * L_SEQ + p];
      md[(size_t)i * N_COLS + k] = (v != 0 && hit == 0u) ? (1.0f / pop[id]) : 0.0f;
    }
  } else if (b < 291) {
    int r = (b - 266) * 256 + tid;  // 6400 rows
    int i = r / L_SEQ, j = r - i * L_SEQ;
    int tgt = i * 101 + j + 1;
    int p = j + 1;
    int vt = (p == 100) ? 1 : lm[i * L_SEQ + p];
    const float4* pr = (const float4*)(prec + (size_t)r * D_);
    const float4* sr = (const float4*)(score + (size_t)tgt * D_);
    float a = 0.f;
#pragma unroll
    for (int t = 0; t < 16; ++t) {
      float4 pa = pr[t], sa = sr[t];
      a += pa.x * sa.x + pa.y * sa.y + pa.z * sa.z + pa.w * sa.w;
    }
    xt[r] = vt ? (a - __logf(pop[sid[tgt]])) : NEG_INF;
  } else {
    if (tid == 0) { acc[0] = 0.f; acc[1] = 0.f; done[0] = 0u; }
  }
}

#define LOADT(stv, B0, B1, MA, MB)                                                   \
  {                                                                                  \
    const int cb_ = (stv) * 64;                                                      \
    _Pragma("unroll")                                                                \
    for (int t = 0; t < 4; ++t) {                                                    \
      const unsigned short* sp_ = sc_bf + (size_t)(cb_ + t * 16 + lr) * D_ + lk * 8; \
      B0[t].v = *(const short8*)(sp_);                                               \
      B1[t].v = *(const short8*)(sp_ + 32);                                          \
    }                                                                                \
    _Pragma("unroll")                                                                \
    for (int t = 0; t < 4; ++t) {                                                    \
      const int c_ = cb_ + t * 16 + lr;                                              \
      MA[t] = md_a[c_];                                                              \
      MB[t] = md_b[c_];                                                              \
    }                                                                                \
  }

#define COMPT(B0, B1, MA, MB)                                                        \
  {                                                                                  \
    f32x4 acc_[4];                                                                   \
    _Pragma("unroll")                                                                \
    for (int t = 0; t < 4; ++t) {                                                    \
      f32x4 z_ = {0.f, 0.f, 0.f, 0.f};                                               \
      z_ = __builtin_amdgcn_mfma_f32_16x16x32_bf16(fa0.v, B0[t].v, z_, 0, 0, 0);     \
      z_ = __builtin_amdgcn_mfma_f32_16x16x32_bf16(fa1.v, B1[t].v, z_, 0, 0, 0);     \
      acc_[t] = z_;                                                                  \
    }                                                                                \
    _Pragma("unroll")                                                                \
    for (int q = 0; q < 4; ++q) {                                                    \
      const bool ub_ = (rbase4 + q) >= lim;                                          \
      _Pragma("unroll")                                                              \
      for (int t = 0; t < 4; ++t) {                                                  \
        const float mm_ = ub_ ? MB[t] : MA[t];                                       \
        s[t][q] = fmaf(__expf(acc_[t][q]), mm_, s[t][q]);                            \
      }                                                                              \
    }                                                                                \
  }

// grid (100, 8), 256 threads = 4 waves. Wave owns 16 rows x 1/8 of columns.
// Register ping-pong double-buffer: tile t+1's loads issue before tile t computes.
__global__ __launch_bounds__(256) void main_kernel(
    const float* __restrict__ prec, const unsigned short* __restrict__ sc_bf,
    const float* __restrict__ md, float* __restrict__ ps) {
  const int w = threadIdx.x >> 6;
  const int lane = threadIdx.x & 63;
  const int lr = lane & 15;      // frag row/col
  const int lk = lane >> 4;      // k-chunk
  const int rowbase = blockIdx.x * 64 + w * 16;
  const int split = blockIdx.y;

  // A fragments: prec rows (f32 -> bf16), held in regs
  const float* prow = prec + (size_t)(rowbase + lr) * D_ + lk * 8;
  F8 fa0, fa1;
  {
    float4 a0 = *(const float4*)(prow);
    float4 a1 = *(const float4*)(prow + 4);
    float4 b0 = *(const float4*)(prow + 32);
    float4 b1 = *(const float4*)(prow + 36);
    fa0.u[0] = f2bf(a0.x); fa0.u[1] = f2bf(a0.y); fa0.u[2] = f2bf(a0.z); fa0.u[3] = f2bf(a0.w);
    fa0.u[4] = f2bf(a1.x); fa0.u[5] = f2bf(a1.y); fa0.u[6] = f2bf(a1.z); fa0.u[7] = f2bf(a1.w);
    fa1.u[0] = f2bf(b0.x); fa1.u[1] = f2bf(b0.y); fa1.u[2] = f2bf(b0.z); fa1.u[3] = f2bf(b0.w);
    fa1.u[4] = f2bf(b1.x); fa1.u[5] = f2bf(b1.y); fa1.u[6] = f2bf(b1.z); fa1.u[7] = f2bf(b1.w);
  }

  const int rbase4 = rowbase + lk * 4;           // this lane's 4 acc rows
  const int i_a = rbase4 / L_SEQ;
  const int i_b = (rbase4 + 3) / L_SEQ;
  const int lim = (i_a + 1) * L_SEQ;
  const float* md_a = md + (size_t)i_a * N_COLS;
  const float* md_b = md + (size_t)i_b * N_COLS;

  float s[4][4];
#pragma unroll
  for (int t = 0; t < 4; ++t)
#pragma unroll
    for (int q = 0; q < 4; ++q) s[t][q] = 0.f;

  F8 b0A[4], b1A[4], b0B[4], b1B[4];
  float maA[4], mbA[4], maB[4], mbB[4];

  int st = split;
  const int nit = (100 - split) / NSPLIT + 1;   // 12 or 13
  LOADT(st, b0A, b1A, maA, mbA);
  int it = 1;
  for (; it + 1 < nit; it += 2) {
    LOADT(st + NSPLIT, b0B, b1B, maB, mbB);
    COMPT(b0A, b1A, maA, mbA);
    LOADT(st + 2 * NSPLIT, b0A, b1A, maA, mbA);
    COMPT(b0B, b1B, maB, mbB);
    st += 2 * NSPLIT;
  }
  if (it < nit) {
    LOADT(st + NSPLIT, b0B, b1B, maB, mbB);
    COMPT(b0A, b1A, maA, mbA);
    COMPT(b0B, b1B, maB, mbB);
  } else {
    COMPT(b0A, b1A, maA, mbA);
  }

  float sq[4];
#pragma unroll
  for (int q = 0; q < 4; ++q)
    sq[q] = (s[0][q] + s[1][q]) + (s[2][q] + s[3][q]);
#pragma unroll
  for (int q = 0; q < 4; ++q) {
#pragma unroll
    for (int off = 1; off < 16; off <<= 1)
      sq[q] += __shfl_xor(sq[q], off);
  }
  if (lr == 0) {
#pragma unroll
    for (int q = 0; q < 4; ++q)
      ps[(size_t)(rbase4 + q) * NSPLIT + split] = sq[q];
  }
}

// 25 blocks x 256: per-row combine + target injection + fused global reduce
__global__ __launch_bounds__(256) void merge_kernel(
    const float* __restrict__ ps, const float* __restrict__ xt,
    const int* __restrict__ lm, float* __restrict__ acc,
    unsigned* __restrict__ done, float* __restrict__ out) {
  const int r = blockIdx.x * 256 + threadIdx.x;
  const float4* pp = (const float4*)(ps + (size_t)r * NSPLIT);
  float4 a = pp[0], b = pp[1];
  float s = ((a.x + a.y) + (a.z + a.w)) + ((b.x + b.y) + (b.z + b.w));
  float x = xt[r];
  s += __expf(x);  // exp(NEG_INF) == 0 when target col invalid
  const int v = (lm[r] != 0);
  float nll = v ? (__logf(s) - x) : 0.f;
  float c = v ? 1.f : 0.f;
#pragma unroll
  for (int off = 1; off < 64; off <<= 1) {
    nll += __shfl_xor(nll, off);
    c += __shfl_xor(c, off);
  }
  __shared__ float red[8];
  const int w = threadIdx.x >> 6, lane = threadIdx.x & 63;
  if (lane == 0) { red[w] = nll; red[4 + w] = c; }
  __syncthreads();
  if (threadIdx.x == 0) {
    float bs = (red[0] + red[1]) + (red[2] + red[3]);
    float bc = (red[4] + red[5]) + (red[6] + red[7]);
    atomicAdd(&acc[0], bs);
    atomicAdd(&acc[1], bc);
    __threadfence();
    unsigned t = atomicAdd(done, 1u);
    if (t == 24) {
      float S = atomicAdd(&acc[0], 0.f);
      float C = atomicAdd(&acc[1], 0.f);
      out[0] = S / C;
    }
  }
}

extern "C" void kernel_launch(void* const* d_in, const int* in_sizes, int n_in,
                              void* d_out, int out_size, void* d_ws, size_t ws_size,
                              hipStream_t stream) {
  const float* prec  = (const float*)d_in[0];
  const float* score = (const float*)d_in[1];
  const float* pop   = (const float*)d_in[2];
  const int*   sid   = (const int*)d_in[3];
  const int*   lm    = (const int*)d_in[4];

  char* ws = (char*)d_ws;
  unsigned short* sc_bf = (unsigned short*)(ws + OFF_SCBF);
  float*          md    = (float*)(ws + OFF_MD);
  float*          xt    = (float*)(ws + OFF_XT);
  float*          ps    = (float*)(ws + OFF_PS);
  float*          acc   = (float*)(ws + OFF_ACC);
  unsigned*       done  = (unsigned*)(ws + OFF_DONE);
  float*          out   = (float*)d_out;

  hipLaunchKernelGGL(prep_kernel, dim3(292), dim3(256), 0, stream,
                     prec, score, pop, sid, lm, sc_bf, md, xt, acc, done);
  hipLaunchKernelGGL(main_kernel, dim3(100, NSPLIT), dim3(256), 0, stream,
                     prec, sc_bf, md, ps);
  hipLaunchKernelGGL(merge_kernel, dim3(25), dim3(256), 0, stream,
                     ps, xt, lm, acc, done, out);
}

// Round 5
// 34.287 us; speedup vs baseline: 2.1422x; 2.1422x over previous
//
#include <hip/hip_runtime.h>

#define NEG_INF (-10000.0f)
#define L_SEQ   100
#define N_COLS  6464      // BS*(L+1)
#define D_      64
#define N_ROWS  6400      // BS*L
#define NS      16        // column splits

// ws byte offsets
#define OFF_PS  0         // float[6400*16] = 409600
#define OFF_XT  409600    // float[6400]    =  25600

typedef __attribute__((ext_vector_type(8))) short short8;
typedef __attribute__((ext_vector_type(4))) float f32x4;
union F8 { short8 v; unsigned short u[8]; unsigned w[4]; };

__device__ __forceinline__ unsigned short f2bf(float f) {  // RTN
  unsigned u = __float_as_uint(f);
  return (unsigned short)((u + 0x7FFFu + ((u >> 16) & 1u)) >> 16);
}
__device__ __forceinline__ unsigned packbf(float lo, float hi) {  // trunc pack
  return (__float_as_uint(hi) & 0xFFFF0000u) | (__float_as_uint(lo) >> 16);
}

// grid (100, 16), 256 threads = 4 waves; wave owns 16 rows x 1/16 of columns.
// Reads ONLY pristine inputs (L2-replicable). B staged f32->bf16 into swizzled
// LDS shared by the 4 waves; dup-masks via per-block LDS bitsets; target logit
// via one extra MFMA (split 0 only). No max-tracking (logits bounded ~±50).
__global__ __launch_bounds__(256, 4) void fused_kernel(
    const float* __restrict__ prec, const float* __restrict__ score,
    const float* __restrict__ pop, const int* __restrict__ sid,
    const int* __restrict__ lm,
    float* __restrict__ ps, float* __restrict__ xtrow) {
  __shared__ unsigned bs[2 * 3126];        // 2 seq bitsets, 100032 bits each
  __shared__ unsigned short btile[64 * 64];// B supertile, bf16, XOR-swizzled
  __shared__ float mdl[2 * 64];            // mask/pop factor per (seq, col)

  const int tid = threadIdx.x;
  const int split = blockIdx.y;
  const int blkrow = blockIdx.x * 64;
  const int w = tid >> 6, lane = tid & 63;
  const int lr = lane & 15, lk = lane >> 4;
  const int rowbase = blkrow + w * 16;
  const int i0 = blkrow / L_SEQ;
  const int i1 = (blkrow + 63) / L_SEQ;
  const int lim = (i0 + 1) * L_SEQ;
  const int rbase4 = rowbase + lk * 4;     // this lane's 4 acc rows

  // ---- build dup bitsets ----
  for (int x = tid; x < 2 * 3126; x += 256) bs[x] = 0u;
  __syncthreads();
  if (tid < 202) {
    int sel = tid / 101, pos = tid - sel * 101;
    int iq = sel ? i1 : i0;
    int id = sid[iq * 101 + pos];
    atomicOr(&bs[sel * 3126 + (id >> 5)], 1u << (id & 31));
  }

  // ---- A fragments (prec rows, f32->bf16 RTN, once) ----
  const float* prow = prec + (size_t)(rowbase + lr) * D_ + lk * 8;
  F8 fa0, fa1;
  {
    float4 a0 = *(const float4*)(prow);
    float4 a1 = *(const float4*)(prow + 4);
    float4 b0 = *(const float4*)(prow + 32);
    float4 b1 = *(const float4*)(prow + 36);
    fa0.u[0] = f2bf(a0.x); fa0.u[1] = f2bf(a0.y); fa0.u[2] = f2bf(a0.z); fa0.u[3] = f2bf(a0.w);
    fa0.u[4] = f2bf(a1.x); fa0.u[5] = f2bf(a1.y); fa0.u[6] = f2bf(a1.z); fa0.u[7] = f2bf(a1.w);
    fa1.u[0] = f2bf(b0.x); fa1.u[1] = f2bf(b0.y); fa1.u[2] = f2bf(b0.z); fa1.u[3] = f2bf(b0.w);
    fa1.u[4] = f2bf(b1.x); fa1.u[5] = f2bf(b1.y); fa1.u[6] = f2bf(b1.z); fa1.u[7] = f2bf(b1.w);
  }

  float s[4][4];
#pragma unroll
  for (int t4 = 0; t4 < 4; ++t4)
#pragma unroll
    for (int q = 0; q < 4; ++q) s[t4][q] = 0.f;

  // staging registers (tile t+1 in flight during compute of t)
  float4 sv[4];
  int svN = 0, lmvN = 0;

  auto STAGE_ISSUE = [&](int stv) {
    const float* base = score + (size_t)stv * 64 * D_;
#pragma unroll
    for (int j = 0; j < 4; ++j)
      sv[j] = *(const float4*)(base + j * 1024 + tid * 4);
    if (tid < 64) {
      int c = stv * 64 + tid;
      svN = sid[c];
      int i2 = c / 101, p = c - i2 * 101;
      lmvN = (p == L_SEQ) ? 1 : lm[i2 * L_SEQ + p];
    }
  };
  auto STAGE_WRITE = [&]() {
#pragma unroll
    for (int j = 0; j < 4; ++j) {
      int colw = j * 16 + (tid >> 4);
      int byteoff = colw * 128 + ((((tid & 15) * 8)) ^ ((colw & 7) << 4));
      uint2 pk;
      pk.x = packbf(sv[j].x, sv[j].y);
      pk.y = packbf(sv[j].z, sv[j].w);
      *(uint2*)((char*)btile + byteoff) = pk;
    }
    if (tid < 64) {
      float inv = 1.0f / pop[svN];
      unsigned h0 = (bs[svN >> 5] >> (svN & 31)) & 1u;
      unsigned h1 = (bs[3126 + (svN >> 5)] >> (svN & 31)) & 1u;
      mdl[tid] = (lmvN && !h0) ? inv : 0.f;
      mdl[64 + tid] = (lmvN && !h1) ? inv : 0.f;
    }
  };
  auto COMPUTE = [&]() {
    const int sw = (lr & 7) << 4;
    F8 fb0[4], fb1[4];
    float ma[4], mb[4];
#pragma unroll
    for (int t4 = 0; t4 < 4; ++t4) {
      int col = t4 * 16 + lr;
      char* rowp = (char*)btile + col * 128;
      fb0[t4].v = *(const short8*)(rowp + ((lk * 16) ^ sw));
      fb1[t4].v = *(const short8*)(rowp + ((64 + lk * 16) ^ sw));
      ma[t4] = mdl[t4 * 16 + lr];
      mb[t4] = mdl[64 + t4 * 16 + lr];
    }
    f32x4 acc[4];
#pragma unroll
    for (int t4 = 0; t4 < 4; ++t4) {
      f32x4 z = {0.f, 0.f, 0.f, 0.f};
      z = __builtin_amdgcn_mfma_f32_16x16x32_bf16(fa0.v, fb0[t4].v, z, 0, 0, 0);
      z = __builtin_amdgcn_mfma_f32_16x16x32_bf16(fa1.v, fb1[t4].v, z, 0, 0, 0);
      acc[t4] = z;
    }
#pragma unroll
    for (int q = 0; q < 4; ++q) {
      const bool ub = (rbase4 + q) >= lim;
#pragma unroll
      for (int t4 = 0; t4 < 4; ++t4) {
        float mm = ub ? mb[t4] : ma[t4];
        s[t4][q] = fmaf(__expf(acc[t4][q]), mm, s[t4][q]);
      }
    }
  };

  // ---- main loop over this split's supertiles ----
  const int nit = (100 - split) / NS + 1;  // 6 or 7
  int st = split;
  STAGE_ISSUE(st);
  __syncthreads();       // bitsets ready (STAGE_WRITE reads them)
  STAGE_WRITE();
  __syncthreads();       // btile/mdl ready
  for (int t = 0; t < nit; ++t) {
    const bool more = (t + 1 < nit);
    if (more) STAGE_ISSUE(st + NS);
    COMPUTE();
    if (more) {
      __syncthreads();   // all waves done reading LDS tile t
      STAGE_WRITE();
      __syncthreads();   // tile t+1 ready
    }
    st += NS;
  }

  // ---- reduce across the 16 col-lanes per row; store partial ----
  float sq[4];
#pragma unroll
  for (int q = 0; q < 4; ++q)
    sq[q] = (s[0][q] + s[1][q]) + (s[2][q] + s[3][q]);
#pragma unroll
  for (int q = 0; q < 4; ++q) {
#pragma unroll
    for (int off = 1; off < 16; off <<= 1)
      sq[q] += __shfl_xor(sq[q], off);
  }
  if (lr == 0) {
#pragma unroll
    for (int q = 0; q < 4; ++q)
      ps[(size_t)(rbase4 + q) * NS + split] = sq[q];
  }

  // ---- target logits: one extra MFMA vs each row's own target column ----
  if (split == 0) {
    int row_l = rowbase + lr;
    int i_l = row_l / L_SEQ, j_l = row_l - i_l * L_SEQ;
    int tgtc = i_l * 101 + j_l + 1;
    int p_l = j_l + 1;
    int vt = (p_l == L_SEQ) ? 1 : lm[i_l * L_SEQ + p_l];
    const float* srp = score + (size_t)tgtc * D_ + lk * 8;
    float4 s0 = *(const float4*)(srp);
    float4 s1 = *(const float4*)(srp + 4);
    float4 s2 = *(const float4*)(srp + 32);
    float4 s3 = *(const float4*)(srp + 36);
    F8 ft0, ft1;
    ft0.w[0] = packbf(s0.x, s0.y); ft0.w[1] = packbf(s0.z, s0.w);
    ft0.w[2] = packbf(s1.x, s1.y); ft0.w[3] = packbf(s1.z, s1.w);
    ft1.w[0] = packbf(s2.x, s2.y); ft1.w[1] = packbf(s2.z, s2.w);
    ft1.w[2] = packbf(s3.x, s3.y); ft1.w[3] = packbf(s3.z, s3.w);
    f32x4 z = {0.f, 0.f, 0.f, 0.f};
    z = __builtin_amdgcn_mfma_f32_16x16x32_bf16(fa0.v, ft0.v, z, 0, 0, 0);
    z = __builtin_amdgcn_mfma_f32_16x16x32_bf16(fa1.v, ft1.v, z, 0, 0, 0);
    int qs = lr - lk * 4;   // diagonal: C[row][col] with row=lk*4+q, col=lr
    if (qs >= 0 && qs < 4) {
      float zd = (qs == 0) ? z[0] : (qs == 1) ? z[1] : (qs == 2) ? z[2] : z[3];
      float xv = zd - __logf(pop[sid[tgtc]]);
      xtrow[row_l] = vt ? xv : NEG_INF;
    }
  }
}

// one block, 1024 threads: per-row sum of 16 partials + target + mean
__global__ __launch_bounds__(1024) void merge_kernel(
    const float* __restrict__ ps, const float* __restrict__ xtrow,
    const int* __restrict__ lm, float* __restrict__ out) {
  float lsum = 0.f, lcnt = 0.f;
  for (int r = threadIdx.x; r < N_ROWS; r += 1024) {
    const float4* pp = (const float4*)(ps + (size_t)r * NS);
    float4 a = pp[0], b = pp[1], c = pp[2], d = pp[3];
    float sv = ((a.x + a.y) + (a.z + a.w)) + ((b.x + b.y) + (b.z + b.w)) +
               ((c.x + c.y) + (c.z + c.w)) + ((d.x + d.y) + (d.z + d.w));
    float x = xtrow[r];
    sv += __expf(x);           // exp(NEG_INF)==0 when target col invalid
    sv = fmaxf(sv, 1e-37f);
    if (lm[r] != 0) { lsum += __logf(sv) - x; lcnt += 1.f; }
  }
#pragma unroll
  for (int off = 1; off < 64; off <<= 1) {
    lsum += __shfl_xor(lsum, off);
    lcnt += __shfl_xor(lcnt, off);
  }
  __shared__ float red[32];
  const int wid = threadIdx.x >> 6, lane = threadIdx.x & 63;
  if (lane == 0) { red[wid] = lsum; red[16 + wid] = lcnt; }
  __syncthreads();
  if (threadIdx.x == 0) {
    float S = 0.f, C = 0.f;
#pragma unroll
    for (int k = 0; k < 16; ++k) { S += red[k]; C += red[16 + k]; }
    out[0] = S / C;
  }
}

extern "C" void kernel_launch(void* const* d_in, const int* in_sizes, int n_in,
                              void* d_out, int out_size, void* d_ws, size_t ws_size,
                              hipStream_t stream) {
  const float* prec  = (const float*)d_in[0];
  const float* score = (const float*)d_in[1];
  const float* pop   = (const float*)d_in[2];
  const int*   sid   = (const int*)d_in[3];
  const int*   lm    = (const int*)d_in[4];

  char* ws = (char*)d_ws;
  float* ps    = (float*)(ws + OFF_PS);
  float* xtrow = (float*)(ws + OFF_XT);
  float* out   = (float*)d_out;

  hipLaunchKernelGGL(fused_kernel, dim3(100, NS), dim3(256), 0, stream,
                     prec, score, pop, sid, lm, ps, xtrow);
  hipLaunchKernelGGL(merge_kernel, dim3(1), dim3(1024), 0, stream,
                     ps, xtrow, lm, out);
}